// Round 8
// baseline (188.438 us; speedup 1.0000x reference)
//
#include <hip/hip_runtime.h>
#include <hip/hip_bf16.h>

typedef __hip_bfloat16 bf16;
typedef short bf16x8 __attribute__((ext_vector_type(8)));
typedef float f32x4 __attribute__((ext_vector_type(4)));
typedef unsigned int u32;

static __device__ __forceinline__ float bfu2f(unsigned short u) { return __uint_as_float((u32)u << 16); }
static __device__ __forceinline__ u32 pack2(float a, float b) {
    return (u32)__bfloat16_as_ushort(__float2bfloat16(a))
         | ((u32)__bfloat16_as_ushort(__float2bfloat16(b)) << 16);
}

// async global->LDS 16B copy (wave-uniform LDS base + lane*16 by HW).
static __device__ __forceinline__ void gll16(const bf16* g, bf16* l) {
    __builtin_amdgcn_global_load_lds((const __attribute__((address_space(1))) void*)g,
                                     (__attribute__((address_space(3))) void*)l,
                                     16, 0, 0);
}

// ---------------------------------------------------------------------------
// Fused QKV projection GEMM (NT), 128x64 tiles (round 8: was 128x128),
// BK=64, fp32 inputs read directly. Both A AND W prefetched one chunk
// ahead in registers (symmetric T14) -> loads in flight across the whole
// MFMA phase. Smaller tile: grid (64, 24) = 1536 blocks, LDS 24KB,
// acc 8x f32x4 -> VGPR <=128 -> 16 waves/CU resident (was 12) with a
// 6-block/CU work queue: more TLP + deeper memory queue.
// Swizzled LDS layout LDS[row][g] = glob[row][g ^ (row&7)] unchanged.
// Wave tile: 64 rows x 32 cols (wm=(wave>>1)*64, wn=(wave&1)*32).
// ---------------------------------------------------------------------------
__global__ __launch_bounds__(256) void gemm_qkv(const float* __restrict__ Aq, const float* __restrict__ Ak,
                                                const float* __restrict__ Wq, const float* __restrict__ Wk,
                                                const float* __restrict__ Wv,
                                                const float* __restrict__ bq, const float* __restrict__ bk,
                                                const float* __restrict__ bv,
                                                bf16* __restrict__ oQ, bf16* __restrict__ oK,
                                                bf16* __restrict__ oV)
{
    __shared__ bf16 Xs[128 * 64];
    __shared__ bf16 Ws[64 * 64];

    const int tid = threadIdx.x, lane = tid & 63, wave = tid >> 6;
    const int yy = blockIdx.y, wi = yy >> 3;
    const float* A    = wi == 0 ? Aq : Ak;
    const float* W    = wi == 0 ? Wq : wi == 1 ? Wk : Wv;
    const float* bias = wi == 0 ? bq : wi == 1 ? bk : bv;
    bf16* out         = wi == 0 ? oQ : wi == 1 ? oK : oV;
    const bool vmode  = (wi == 2);
    const int bm = blockIdx.x * 128;
    const int bn = (yy & 7) * 64;

    const int srow = tid >> 3;
    const int sg8  = (((tid & 7) ^ (srow & 7)) * 8);
    const int wm = (wave >> 1) * 64, wn = (wave & 1) * 32;
    const int fr = lane & 15, fq = lane >> 4;

    f32x4 acc[8] = {};   // non-vmode: [i<2][j<4] as acc[i*4+j]; vmode: [i<4][j<2] as acc[i*2+j]
    const float* Ap = A + (size_t)(bm + srow) * 512 + sg8;
    const float* Wp = W + (size_t)(bn + srow) * 512 + sg8;
    const int ld = 8 * tid;

    // symmetric T14 prefetch: chunk 0 of A (4 granule-sets) and W (2)
    float4 ra[4][2], rw[2][2];
    #pragma unroll
    for (int c = 0; c < 4; c++) {
        const float* ap = Ap + (size_t)(32 * c) * 512;
        ra[c][0] = *(const float4*)(ap);
        ra[c][1] = *(const float4*)(ap + 4);
    }
    #pragma unroll
    for (int c = 0; c < 2; c++) {
        const float* wp = Wp + (size_t)(32 * c) * 512;
        rw[c][0] = *(const float4*)(wp);
        rw[c][1] = *(const float4*)(wp + 4);
    }

    for (int kt = 0; kt < 8; kt++) {
        const int k0 = kt * 64;
        __syncthreads();
        // pack prefetched chunk -> LDS (loads landed during prev MFMA phase)
        #pragma unroll
        for (int c = 0; c < 4; c++) {
            uint4 av;
            av.x = pack2(ra[c][0].x, ra[c][0].y); av.y = pack2(ra[c][0].z, ra[c][0].w);
            av.z = pack2(ra[c][1].x, ra[c][1].y); av.w = pack2(ra[c][1].z, ra[c][1].w);
            *(uint4*)(Xs + ld + 2048 * c) = av;
        }
        #pragma unroll
        for (int c = 0; c < 2; c++) {
            uint4 wv;
            wv.x = pack2(rw[c][0].x, rw[c][0].y); wv.y = pack2(rw[c][0].z, rw[c][0].w);
            wv.z = pack2(rw[c][1].x, rw[c][1].y); wv.w = pack2(rw[c][1].z, rw[c][1].w);
            *(uint4*)(Ws + ld + 2048 * c) = wv;
        }
        // issue next chunk's loads — in flight across barrier + MFMA phase
        if (kt < 7) {
            #pragma unroll
            for (int c = 0; c < 4; c++) {
                const float* ap = Ap + k0 + 64 + (size_t)(32 * c) * 512;
                ra[c][0] = *(const float4*)(ap);
                ra[c][1] = *(const float4*)(ap + 4);
            }
            #pragma unroll
            for (int c = 0; c < 2; c++) {
                const float* wp = Wp + k0 + 64 + (size_t)(32 * c) * 512;
                rw[c][0] = *(const float4*)(wp);
                rw[c][1] = *(const float4*)(wp + 4);
            }
        }
        __syncthreads();

        #pragma unroll
        for (int c2 = 0; c2 < 2; c2++) {
            bf16x8 fx[4], fw[2];
            #pragma unroll
            for (int j = 0; j < 4; j++) {
                const int rx = wm + 16 * j + fr;
                fx[j] = *(const bf16x8*)(&Xs[rx * 64 + (((c2 * 4 + fq) ^ (rx & 7)) * 8)]);
            }
            #pragma unroll
            for (int i = 0; i < 2; i++) {
                const int rw2 = wn + 16 * i + fr;
                fw[i] = *(const bf16x8*)(&Ws[rw2 * 64 + (((c2 * 4 + fq) ^ (rw2 & 7)) * 8)]);
            }
            if (vmode) {
                #pragma unroll
                for (int i = 0; i < 4; i++)
                    #pragma unroll
                    for (int j = 0; j < 2; j++)
                        acc[i * 2 + j] = __builtin_amdgcn_mfma_f32_16x16x32_bf16(fx[i], fw[j], acc[i * 2 + j], 0, 0, 0);
            } else {
                #pragma unroll
                for (int i = 0; i < 2; i++)
                    #pragma unroll
                    for (int j = 0; j < 4; j++)
                        acc[i * 4 + j] = __builtin_amdgcn_mfma_f32_16x16x32_bf16(fw[i], fx[j], acc[i * 4 + j], 0, 0, 0);
            }
        }
    }

    if (!vmode) {
        // C^T: acc[i*4+j] row = weight-col (d_full), col = data-row (n).
        #pragma unroll
        for (int i = 0; i < 2; i++) {
            const int colb = bn + wn + 16 * i + 4 * fq;
            const float4 b4 = *(const float4*)(bias + colb);
            const int h = colb >> 6, d0 = colb & 63;
            #pragma unroll
            for (int j = 0; j < 4; j++) {
                const int n = bm + wm + 16 * j + fr;
                const int b = n >> 10, nn = n & 1023;
                const f32x4 a4 = acc[i * 4 + j];
                uint2 pk;
                pk.x = pack2(a4[0] + b4.x, a4[1] + b4.y);
                pk.y = pack2(a4[2] + b4.z, a4[3] + b4.w);
                *(uint2*)(out + ((size_t)(b * 8 + h) * 1024 + nn) * 64 + d0) = pk;
            }
        }
    } else {
        // C: acc[i*2+j] row = data-row (n), col = weight-col.
        #pragma unroll
        for (int i = 0; i < 4; i++) {
            const int n0 = bm + wm + 16 * i + 4 * fq;
            const int b = n0 >> 10, nn = n0 & 1023;
            #pragma unroll
            for (int j = 0; j < 2; j++) {
                const int col = bn + wn + 16 * j + fr;
                const float bv2 = bias[col];
                const int h = col >> 6, d = col & 63;
                const f32x4 a4 = acc[i * 2 + j];
                uint2 pk;
                pk.x = pack2(a4[0] + bv2, a4[1] + bv2);
                pk.y = pack2(a4[2] + bv2, a4[3] + bv2);
                *(uint2*)(out + ((size_t)(b * 8 + h) * 64 + d) * 1024 + nn) = pk;
            }
        }
    }
}

// ---------------------------------------------------------------------------
// MFMA flash attention — S^T form, fixed-max softmax. 16 q-rows per wave,
// grid 1024 (64 bh x 16 q-blocks), 4 waves/block, LDS 25KB -> 4 blk/CU.
// Qh [b,h,n,64], Kh [b,h,m,64], VhT [b,h,d,m]. XCD-local bh grouping.
// ---------------------------------------------------------------------------
__global__ __launch_bounds__(256) void attn_mfma(const bf16* __restrict__ Qh,
                                                 const bf16* __restrict__ Kh,
                                                 const bf16* __restrict__ VhT,
                                                 bf16* __restrict__ Oc)
{
    __shared__ bf16 Ks[64 * 64];
    __shared__ bf16 Vs[64 * 64];
    __shared__ bf16 Ps[4][16 * 72];

    const int tid = threadIdx.x, lane = tid & 63, w = tid >> 6;
    const int id = blockIdx.x;
    const int bh = (id & 7) * 8 + (id >> 7);        // XCD-local bh grouping
    const int wq = ((id >> 3) & 15) * 64 + w * 16;  // wave's q-tile (16 rows)

    const bf16* Qb = Qh  + ((size_t)bh * 1024 + wq) * 64;
    const bf16* Kb = Kh  + (size_t)bh * 1024 * 64;
    const bf16* Vb = VhT + (size_t)bh * 64 * 1024;

    const int fl = lane & 15, fq = lane >> 4;
    const int flk = fl & 7;
    const int gA = (fq ^ flk) * 8;
    const int gB = ((4 | fq) ^ flk) * 8;

    bf16x8 qf[2];
    qf[0] = *(const bf16x8*)(Qb + fl * 64 + fq * 8);
    qf[1] = *(const bf16x8*)(Qb + fl * 64 + 32 + fq * 8);

    f32x4 o[4] = {};
    float lsum = 0.f;
    const float sc2 = 0.04419417382415922f * 1.4426950408889634f; // /sqrt(512)*log2e

    const int srow = tid >> 3;
    const int sg8  = (((tid & 7) ^ (srow & 7)) * 8);
    const bf16* KbR  = Kb + (size_t)srow * 64 + sg8;
    const bf16* VbR0 = Vb + (size_t)srow * 1024 + sg8;
    const bf16* VbR1 = Vb + (size_t)(srow + 32) * 1024 + sg8;
    const int ld = 8 * tid;

    for (int kt = 0; kt < 16; kt++) {
        const int m0 = kt * 64;
        __syncthreads();
        gll16(KbR + (size_t)m0 * 64,        Ks + ld);
        gll16(KbR + (size_t)(m0 + 32) * 64, Ks + 2048 + ld);
        gll16(VbR0 + m0,                    Vs + ld);
        gll16(VbR1 + m0,                    Vs + 2048 + ld);
        __syncthreads();

        bf16x8 kf[4][2];
        #pragma unroll
        for (int tm = 0; tm < 4; tm++) {
            kf[tm][0] = *(const bf16x8*)(&Ks[(16 * tm + fl) * 64 + gA]);
            kf[tm][1] = *(const bf16x8*)(&Ks[(16 * tm + fl) * 64 + gB]);
        }

        f32x4 st[4] = {};
        #pragma unroll
        for (int tm = 0; tm < 4; tm++) {
            st[tm] = __builtin_amdgcn_mfma_f32_16x16x32_bf16(kf[tm][0], qf[0], st[tm], 0, 0, 0);
            st[tm] = __builtin_amdgcn_mfma_f32_16x16x32_bf16(kf[tm][1], qf[1], st[tm], 0, 0, 0);
        }
        #pragma unroll
        for (int tm = 0; tm < 4; tm++) {
            float p0 = __builtin_amdgcn_exp2f(st[tm][0] * sc2);
            float p1 = __builtin_amdgcn_exp2f(st[tm][1] * sc2);
            float p2 = __builtin_amdgcn_exp2f(st[tm][2] * sc2);
            float p3 = __builtin_amdgcn_exp2f(st[tm][3] * sc2);
            lsum += (p0 + p1) + (p2 + p3);
            uint2 pk;
            pk.x = pack2(p0, p1);
            pk.y = pack2(p2, p3);
            *(uint2*)(&Ps[w][fl * 72 + 16 * tm + fq * 4]) = pk;
        }

        bf16x8 vf[4][2];
        #pragma unroll
        for (int jd = 0; jd < 4; jd++) {
            vf[jd][0] = *(const bf16x8*)(&Vs[(16 * jd + fl) * 64 + gA]);
            vf[jd][1] = *(const bf16x8*)(&Vs[(16 * jd + fl) * 64 + gB]);
        }
        bf16x8 pf0 = *(const bf16x8*)(&Ps[w][fl * 72 + fq * 8]);
        bf16x8 pf1 = *(const bf16x8*)(&Ps[w][fl * 72 + 32 + fq * 8]);
        #pragma unroll
        for (int jd = 0; jd < 4; jd++) {
            o[jd] = __builtin_amdgcn_mfma_f32_16x16x32_bf16(vf[jd][0], pf0, o[jd], 0, 0, 0);
            o[jd] = __builtin_amdgcn_mfma_f32_16x16x32_bf16(vf[jd][1], pf1, o[jd], 0, 0, 0);
        }
    }

    const int b = bh >> 3, h = bh & 7;
    float ls = lsum;
    ls += __shfl_xor(ls, 16);
    ls += __shfl_xor(ls, 32);
    const float linv = 1.f / ls;
    const size_t obase = ((size_t)(b * 1024 + wq + fl)) * 512 + h * 64;
    #pragma unroll
    for (int jd = 0; jd < 4; jd++) {
        const ushort4 qr = *(const ushort4*)(Qb + fl * 64 + 16 * jd + fq * 4);
        uint2 w2;
        w2.x = pack2(o[jd][0] * linv + bfu2f(qr.x), o[jd][1] * linv + bfu2f(qr.y));
        w2.y = pack2(o[jd][2] * linv + bfu2f(qr.z), o[jd][3] * linv + bfu2f(qr.w));
        *(uint2*)(&Oc[obase + 16 * jd + fq * 4]) = w2;
    }
}

// ---------------------------------------------------------------------------
// FUSED LayerNorm0 + O-projection + residual-relu + LayerNorm1 -> fp32 out.
// 256 blocks x 512 threads (8 waves). Block = 32 rows x ALL 512 cols.
// T14 async-split W loop (W(0) before A-stage; W(kt+1) after W(kt) pack).
// LDS: 32 + 64 + 2 = 98KB -> 1 block/CU.
// ---------------------------------------------------------------------------
__global__ __launch_bounds__(512) void gemm_fo_ln1(const bf16* __restrict__ A,
                                                   const float* __restrict__ Wo,
                                                   const float* __restrict__ g0,
                                                   const float* __restrict__ be0,
                                                   const float* __restrict__ bo,
                                                   const float* __restrict__ g1,
                                                   const float* __restrict__ be1,
                                                   float* __restrict__ out)
{
    __shared__ bf16 As[32 * 512];
    __shared__ bf16 Ws[512 * 64];
    __shared__ float2 red[32][8];

    const int tid = threadIdx.x, lane = tid & 63, w = tid >> 6;
    const int bm = blockIdx.x * 32;
    const int wn = w * 64;
    const int fr = lane & 15, fq = lane >> 4;

    // ---- Phase 1: stage A rows [bm, bm+32), granule-swizzled --------------
    const int ldb = 8 * tid;
    #pragma unroll
    for (int c = 0; c < 4; c++) {
        const int lin = tid + 512 * c;
        const int row = lin >> 6, g = lin & 63;
        gll16(A + (size_t)(bm + row) * 512 + ((g ^ (row & 7)) * 8),
              As + ldb + 4096 * c);
    }

    // T14: issue W chunk 0 now — latency hides under A-stage + ln0
    const int srow = tid >> 3;
    const int sg8  = (((tid & 7) ^ (srow & 7)) * 8);
    const float* Wp = Wo + (size_t)srow * 512 + sg8;
    float4 wr[8][2];
    #pragma unroll
    for (int c = 0; c < 8; c++) {
        const float* wp = Wp + (size_t)(64 * c) * 512;
        wr[c][0] = *(const float4*)(wp);
        wr[c][1] = *(const float4*)(wp + 4);
    }

    __syncthreads();   // A panel resident

    // ---- Phase 2: ln0 in place (row r: 16 threads x 32 cols each) ---------
    {
        const int r = tid >> 4, ci = tid & 15;
        const int lrow = r * 512;
        const int rx = (r & 7) * 8;
        float xv[4][8];
        float s = 0.f, s2 = 0.f;
        #pragma unroll
        for (int gg = 0; gg < 4; gg++) {
            const int g = ci * 4 + gg;
            const bf16x8 v = *(const bf16x8*)(&As[lrow + ((g * 8) ^ rx)]);
            #pragma unroll
            for (int e = 0; e < 8; e++) {
                const float f = bfu2f((unsigned short)v[e]);
                xv[gg][e] = f; s += f; s2 += f * f;
            }
        }
        #pragma unroll
        for (int off = 1; off < 16; off <<= 1) {
            s += __shfl_xor(s, off); s2 += __shfl_xor(s2, off);
        }
        const float mu  = s * (1.f / 512.f);
        const float var = s2 * (1.f / 512.f) - mu * mu;
        const float rs0 = rsqrtf(fmaxf(var, 0.f) + 1e-5f);
        #pragma unroll
        for (int gg = 0; gg < 4; gg++) {
            const int g = ci * 4 + gg;
            const float4 gv0 = *(const float4*)(g0 + g * 8);
            const float4 gv1 = *(const float4*)(g0 + g * 8 + 4);
            const float4 bv0 = *(const float4*)(be0 + g * 8);
            const float4 bv1 = *(const float4*)(be0 + g * 8 + 4);
            uint4 ov;
            ov.x = pack2((xv[gg][0]-mu)*rs0*gv0.x + bv0.x, (xv[gg][1]-mu)*rs0*gv0.y + bv0.y);
            ov.y = pack2((xv[gg][2]-mu)*rs0*gv0.z + bv0.z, (xv[gg][3]-mu)*rs0*gv0.w + bv0.w);
            ov.z = pack2((xv[gg][4]-mu)*rs0*gv1.x + bv1.x, (xv[gg][5]-mu)*rs0*gv1.y + bv1.y);
            ov.w = pack2((xv[gg][6]-mu)*rs0*gv1.z + bv1.z, (xv[gg][7]-mu)*rs0*gv1.w + bv1.w);
            *(uint4*)(&As[lrow + ((g * 8) ^ rx)]) = ov;
        }
    }
    __syncthreads();   // normalized panel visible to all

    // ---- Phase 3: GEMM over W chunks (fp32 Wo, T14-prefetched) ------------
    f32x4 acc[4][2] = {};

    for (int kt = 0; kt < 8; kt++) {
        if (kt) __syncthreads();
        // pack prefetched W chunk -> LDS
        #pragma unroll
        for (int c = 0; c < 8; c++) {
            uint4 wv;
            wv.x = pack2(wr[c][0].x, wr[c][0].y); wv.y = pack2(wr[c][0].z, wr[c][0].w);
            wv.z = pack2(wr[c][1].x, wr[c][1].y); wv.w = pack2(wr[c][1].z, wr[c][1].w);
            *(uint4*)(Ws + ldb + 4096 * c) = wv;
        }
        // issue next W chunk — in flight across barrier + MFMA
        if (kt < 7) {
            const int k1 = (kt + 1) * 64;
            #pragma unroll
            for (int c = 0; c < 8; c++) {
                const float* wp = Wp + k1 + (size_t)(64 * c) * 512;
                wr[c][0] = *(const float4*)(wp);
                wr[c][1] = *(const float4*)(wp + 4);
            }
        }
        __syncthreads();

        const int kb = kt * 8;
        #pragma unroll
        for (int c2 = 0; c2 < 2; c2++) {
            bf16x8 fx[2], fw[4];
            #pragma unroll
            for (int j = 0; j < 2; j++) {
                const int rx = 16 * j + fr;
                fx[j] = *(const bf16x8*)(&As[rx * 512 + (kb + ((c2 * 4 + fq) ^ (rx & 7))) * 8]);
            }
            #pragma unroll
            for (int i = 0; i < 4; i++) {
                const int rw = wn + 16 * i + fr;
                fw[i] = *(const bf16x8*)(&Ws[rw * 64 + (((c2 * 4 + fq) ^ (rw & 7)) * 8)]);
            }
            #pragma unroll
            for (int i = 0; i < 4; i++)
                #pragma unroll
                for (int j = 0; j < 2; j++)
                    acc[i][j] = __builtin_amdgcn_mfma_f32_16x16x32_bf16(fw[i], fx[j], acc[i][j], 0, 0, 0);
        }
    }

    // ---- Phase 4: y = R + relu(X + bo), block LN1, fp32 store -------------
    float yv[4][2][4];
    float s[2] = {0.f, 0.f}, s2[2] = {0.f, 0.f};
    #pragma unroll
    for (int i = 0; i < 4; i++) {
        const int c = wn + 16 * i + 4 * fq;
        const float4 bo4 = *(const float4*)(bo + c);
        const int gc = c >> 3, co = c & 7;
        #pragma unroll
        for (int j = 0; j < 2; j++) {
            const int n = 16 * j + fr;
            const ushort4 rr = *(const ushort4*)(&As[n * 512 + ((gc ^ (n & 7)) * 8 + co)]);
            float y0 = bfu2f(rr.x) + fmaxf(acc[i][j][0] + bo4.x, 0.f);
            float y1 = bfu2f(rr.y) + fmaxf(acc[i][j][1] + bo4.y, 0.f);
            float y2 = bfu2f(rr.z) + fmaxf(acc[i][j][2] + bo4.z, 0.f);
            float y3 = bfu2f(rr.w) + fmaxf(acc[i][j][3] + bo4.w, 0.f);
            s[j]  += (y0 + y1) + (y2 + y3);
            s2[j] += (y0 * y0 + y1 * y1) + (y2 * y2 + y3 * y3);
            yv[i][j][0] = y0; yv[i][j][1] = y1; yv[i][j][2] = y2; yv[i][j][3] = y3;
        }
    }
    #pragma unroll
    for (int j = 0; j < 2; j++) {
        s[j]  += __shfl_xor(s[j], 16);  s[j]  += __shfl_xor(s[j], 32);
        s2[j] += __shfl_xor(s2[j], 16); s2[j] += __shfl_xor(s2[j], 32);
    }
    if (fq == 0) {
        red[fr][w]      = make_float2(s[0], s2[0]);
        red[16 + fr][w] = make_float2(s[1], s2[1]);
    }
    __syncthreads();
    float mu[2], rs[2];
    #pragma unroll
    for (int j = 0; j < 2; j++) {
        const int n = 16 * j + fr;
        float S = 0.f, S2 = 0.f;
        #pragma unroll
        for (int q = 0; q < 8; q++) { const float2 v = red[n][q]; S += v.x; S2 += v.y; }
        mu[j] = S * (1.f / 512.f);
        const float var = S2 * (1.f / 512.f) - mu[j] * mu[j];
        rs[j] = rsqrtf(fmaxf(var, 0.f) + 1e-5f);
    }
    #pragma unroll
    for (int i = 0; i < 4; i++) {
        const int c = wn + 16 * i + 4 * fq;
        const float4 g4 = *(const float4*)(g1 + c);
        const float4 b4 = *(const float4*)(be1 + c);
        #pragma unroll
        for (int j = 0; j < 2; j++) {
            const int n = bm + 16 * j + fr;
            float4 o4;
            o4.x = (yv[i][j][0] - mu[j]) * rs[j] * g4.x + b4.x;
            o4.y = (yv[i][j][1] - mu[j]) * rs[j] * g4.y + b4.y;
            o4.z = (yv[i][j][2] - mu[j]) * rs[j] * g4.z + b4.z;
            o4.w = (yv[i][j][3] - mu[j]) * rs[j] * g4.w + b4.w;
            *(float4*)(out + (size_t)n * 512 + c) = o4;
        }
    }
}

// ---------------------------------------------------------------------------
extern "C" void kernel_launch(void* const* d_in, const int* in_sizes, int n_in,
                              void* d_out, int out_size, void* d_ws, size_t ws_size,
                              hipStream_t stream)
{
    const float* Q   = (const float*)d_in[0];
    const float* K   = (const float*)d_in[1];
    const float* Wq  = (const float*)d_in[2];
    const float* bq  = (const float*)d_in[3];
    const float* Wk  = (const float*)d_in[4];
    const float* bk  = (const float*)d_in[5];
    const float* Wv  = (const float*)d_in[6];
    const float* bv  = (const float*)d_in[7];
    const float* Wo  = (const float*)d_in[8];
    const float* bo  = (const float*)d_in[9];
    const float* g0  = (const float*)d_in[10];
    const float* be0 = (const float*)d_in[11];
    const float* g1  = (const float*)d_in[12];
    const float* be1 = (const float*)d_in[13];
    float* out = (float*)d_out;

    const size_t NQK = (size_t)8 * 1024 * 512;  // 4M elems
    bf16* ws   = (bf16*)d_ws;
    bf16* pQh  = ws;                 // [b,h,n,d]
    bf16* pKh  = pQh + NQK;          // [b,h,m,d]
    bf16* pVhT = pKh + NQK;          // [b,h,d,m]
    bf16* pOc  = pVhT + NQK;         // attn out [b,n,512] (workspace)

    gemm_qkv<<<dim3(64, 24), 256, 0, stream>>>(Q, K, Wq, Wk, Wv, bq, bk, bv, pQh, pKh, pVhT);
    attn_mfma<<<1024, 256, 0, stream>>>(pQh, pKh, pVhT, pOc);
    gemm_fo_ln1<<<256, 512, 0, stream>>>(pOc, Wo, g0, be0, bo, g1, be1, out);
}

// Round 9
// 184.345 us; speedup vs baseline: 1.0222x; 1.0222x over previous
//
#include <hip/hip_runtime.h>
#include <hip/hip_bf16.h>

typedef __hip_bfloat16 bf16;
typedef short bf16x8 __attribute__((ext_vector_type(8)));
typedef float f32x4 __attribute__((ext_vector_type(4)));
typedef unsigned int u32;

static __device__ __forceinline__ float bfu2f(unsigned short u) { return __uint_as_float((u32)u << 16); }
static __device__ __forceinline__ u32 pack2(float a, float b) {
    return (u32)__bfloat16_as_ushort(__float2bfloat16(a))
         | ((u32)__bfloat16_as_ushort(__float2bfloat16(b)) << 16);
}

// async global->LDS 16B copy (wave-uniform LDS base + lane*16 by HW).
static __device__ __forceinline__ void gll16(const bf16* g, bf16* l) {
    __builtin_amdgcn_global_load_lds((const __attribute__((address_space(1))) void*)g,
                                     (__attribute__((address_space(3))) void*)l,
                                     16, 0, 0);
}

// ---------------------------------------------------------------------------
// Fused QKV projection GEMM (NT), 128x128 tiles (round-7 structure restored),
// BK=64, fp32 inputs read directly. Round 9: SYMMETRIC T14 — BOTH A and W
// prefetched one chunk ahead in registers; packs happen at iter top from
// landed registers, next-chunk loads issue immediately after -> every load
// gets a full iteration (MFMA + barriers + packs) of flight time.
// VGPR ~160 -> 3 waves/SIMD = grid-imposed residency (3 blk/CU x 4 waves),
// so the extra 32 prefetch VGPRs are free. Grid (64, 12).
// Swizzled LDS layout LDS[row][g] = glob[row][g ^ (row&7)] unchanged.
// ---------------------------------------------------------------------------
__global__ __launch_bounds__(256) void gemm_qkv(const float* __restrict__ Aq, const float* __restrict__ Ak,
                                                const float* __restrict__ Wq, const float* __restrict__ Wk,
                                                const float* __restrict__ Wv,
                                                const float* __restrict__ bq, const float* __restrict__ bk,
                                                const float* __restrict__ bv,
                                                bf16* __restrict__ oQ, bf16* __restrict__ oK,
                                                bf16* __restrict__ oV)
{
    __shared__ bf16 Xs[128 * 64];
    __shared__ bf16 Ws[128 * 64];

    const int tid = threadIdx.x, lane = tid & 63, wave = tid >> 6;
    const int yy = blockIdx.y, wi = yy >> 2;
    const float* A    = wi == 0 ? Aq : Ak;
    const float* W    = wi == 0 ? Wq : wi == 1 ? Wk : Wv;
    const float* bias = wi == 0 ? bq : wi == 1 ? bk : bv;
    bf16* out         = wi == 0 ? oQ : wi == 1 ? oK : oV;
    const bool vmode  = (wi == 2);
    const int bm = blockIdx.x * 128;
    const int bn = (yy & 3) * 128;

    const int srow = tid >> 3;
    const int sg8  = (((tid & 7) ^ (srow & 7)) * 8);
    const int wm = (wave >> 1) * 64, wn = (wave & 1) * 64;
    const int fr = lane & 15, fq = lane >> 4;

    f32x4 acc[4][4] = {};
    const float* Ap = A + (size_t)(bm + srow) * 512 + sg8;
    const float* Wp = W + (size_t)(bn + srow) * 512 + sg8;
    const int ld = 8 * tid;

    // symmetric T14 prefetch of chunk 0: A (4 granule-sets) and W (4)
    float4 ra[4][2], rw[4][2];
    #pragma unroll
    for (int c = 0; c < 4; c++) {
        const float* ap = Ap + (size_t)(32 * c) * 512;
        const float* wp = Wp + (size_t)(32 * c) * 512;
        ra[c][0] = *(const float4*)(ap); ra[c][1] = *(const float4*)(ap + 4);
        rw[c][0] = *(const float4*)(wp); rw[c][1] = *(const float4*)(wp + 4);
    }

    for (int kt = 0; kt < 8; kt++) {
        const int k0 = kt * 64;
        __syncthreads();
        // pack prefetched chunk -> LDS (loads landed during prev MFMA phase)
        #pragma unroll
        for (int c = 0; c < 4; c++) {
            uint4 av, wv;
            av.x = pack2(ra[c][0].x, ra[c][0].y); av.y = pack2(ra[c][0].z, ra[c][0].w);
            av.z = pack2(ra[c][1].x, ra[c][1].y); av.w = pack2(ra[c][1].z, ra[c][1].w);
            wv.x = pack2(rw[c][0].x, rw[c][0].y); wv.y = pack2(rw[c][0].z, rw[c][0].w);
            wv.z = pack2(rw[c][1].x, rw[c][1].y); wv.w = pack2(rw[c][1].z, rw[c][1].w);
            *(uint4*)(Xs + ld + 2048 * c) = av;
            *(uint4*)(Ws + ld + 2048 * c) = wv;
        }
        // issue next chunk's A+W loads — in flight across barrier + MFMA phase
        if (kt < 7) {
            #pragma unroll
            for (int c = 0; c < 4; c++) {
                const float* ap = Ap + k0 + 64 + (size_t)(32 * c) * 512;
                const float* wp = Wp + k0 + 64 + (size_t)(32 * c) * 512;
                ra[c][0] = *(const float4*)(ap); ra[c][1] = *(const float4*)(ap + 4);
                rw[c][0] = *(const float4*)(wp); rw[c][1] = *(const float4*)(wp + 4);
            }
        }
        __syncthreads();

        #pragma unroll
        for (int c2 = 0; c2 < 2; c2++) {
            bf16x8 fx[4], fw[4];
            #pragma unroll
            for (int i = 0; i < 4; i++) {
                const int rx = wm + 16 * i + fr;
                const int rww = wn + 16 * i + fr;
                fx[i] = *(const bf16x8*)(&Xs[rx * 64 + (((c2 * 4 + fq) ^ (rx & 7)) * 8)]);
                fw[i] = *(const bf16x8*)(&Ws[rww * 64 + (((c2 * 4 + fq) ^ (rww & 7)) * 8)]);
            }
            if (vmode) {
                #pragma unroll
                for (int i = 0; i < 4; i++)
                    #pragma unroll
                    for (int j = 0; j < 4; j++)
                        acc[i][j] = __builtin_amdgcn_mfma_f32_16x16x32_bf16(fx[i], fw[j], acc[i][j], 0, 0, 0);
            } else {
                #pragma unroll
                for (int i = 0; i < 4; i++)
                    #pragma unroll
                    for (int j = 0; j < 4; j++)
                        acc[i][j] = __builtin_amdgcn_mfma_f32_16x16x32_bf16(fw[i], fx[j], acc[i][j], 0, 0, 0);
            }
        }
    }

    if (!vmode) {
        // C^T: acc[i][j] row = weight-col (d_full), col = data-row (n).
        #pragma unroll
        for (int i = 0; i < 4; i++) {
            const int colb = bn + wn + 16 * i + 4 * fq;
            const float4 b4 = *(const float4*)(bias + colb);
            const int h = colb >> 6, d0 = colb & 63;
            #pragma unroll
            for (int j = 0; j < 4; j++) {
                const int n = bm + wm + 16 * j + fr;
                const int b = n >> 10, nn = n & 1023;
                uint2 pk;
                pk.x = pack2(acc[i][j][0] + b4.x, acc[i][j][1] + b4.y);
                pk.y = pack2(acc[i][j][2] + b4.z, acc[i][j][3] + b4.w);
                *(uint2*)(out + ((size_t)(b * 8 + h) * 1024 + nn) * 64 + d0) = pk;
            }
        }
    } else {
        // C: acc[i][j] row = data-row (n), col = weight-col.
        #pragma unroll
        for (int i = 0; i < 4; i++) {
            const int n0 = bm + wm + 16 * i + 4 * fq;
            const int b = n0 >> 10, nn = n0 & 1023;
            #pragma unroll
            for (int j = 0; j < 4; j++) {
                const int col = bn + wn + 16 * j + fr;
                const float bv2 = bias[col];
                const int h = col >> 6, d = col & 63;
                uint2 pk;
                pk.x = pack2(acc[i][j][0] + bv2, acc[i][j][1] + bv2);
                pk.y = pack2(acc[i][j][2] + bv2, acc[i][j][3] + bv2);
                *(uint2*)(out + ((size_t)(b * 8 + h) * 64 + d) * 1024 + nn) = pk;
            }
        }
    }
}

// ---------------------------------------------------------------------------
// MFMA flash attention — S^T form, fixed-max softmax. 16 q-rows per wave,
// grid 1024 (64 bh x 16 q-blocks), 4 waves/block, LDS 25KB -> 4 blk/CU.
// Qh [b,h,n,64], Kh [b,h,m,64], VhT [b,h,d,m]. XCD-local bh grouping.
// ---------------------------------------------------------------------------
__global__ __launch_bounds__(256) void attn_mfma(const bf16* __restrict__ Qh,
                                                 const bf16* __restrict__ Kh,
                                                 const bf16* __restrict__ VhT,
                                                 bf16* __restrict__ Oc)
{
    __shared__ bf16 Ks[64 * 64];
    __shared__ bf16 Vs[64 * 64];
    __shared__ bf16 Ps[4][16 * 72];

    const int tid = threadIdx.x, lane = tid & 63, w = tid >> 6;
    const int id = blockIdx.x;
    const int bh = (id & 7) * 8 + (id >> 7);        // XCD-local bh grouping
    const int wq = ((id >> 3) & 15) * 64 + w * 16;  // wave's q-tile (16 rows)

    const bf16* Qb = Qh  + ((size_t)bh * 1024 + wq) * 64;
    const bf16* Kb = Kh  + (size_t)bh * 1024 * 64;
    const bf16* Vb = VhT + (size_t)bh * 64 * 1024;

    const int fl = lane & 15, fq = lane >> 4;
    const int flk = fl & 7;
    const int gA = (fq ^ flk) * 8;
    const int gB = ((4 | fq) ^ flk) * 8;

    bf16x8 qf[2];
    qf[0] = *(const bf16x8*)(Qb + fl * 64 + fq * 8);
    qf[1] = *(const bf16x8*)(Qb + fl * 64 + 32 + fq * 8);

    f32x4 o[4] = {};
    float lsum = 0.f;
    const float sc2 = 0.04419417382415922f * 1.4426950408889634f; // /sqrt(512)*log2e

    const int srow = tid >> 3;
    const int sg8  = (((tid & 7) ^ (srow & 7)) * 8);
    const bf16* KbR  = Kb + (size_t)srow * 64 + sg8;
    const bf16* VbR0 = Vb + (size_t)srow * 1024 + sg8;
    const bf16* VbR1 = Vb + (size_t)(srow + 32) * 1024 + sg8;
    const int ld = 8 * tid;

    for (int kt = 0; kt < 16; kt++) {
        const int m0 = kt * 64;
        __syncthreads();
        gll16(KbR + (size_t)m0 * 64,        Ks + ld);
        gll16(KbR + (size_t)(m0 + 32) * 64, Ks + 2048 + ld);
        gll16(VbR0 + m0,                    Vs + ld);
        gll16(VbR1 + m0,                    Vs + 2048 + ld);
        __syncthreads();

        bf16x8 kf[4][2];
        #pragma unroll
        for (int tm = 0; tm < 4; tm++) {
            kf[tm][0] = *(const bf16x8*)(&Ks[(16 * tm + fl) * 64 + gA]);
            kf[tm][1] = *(const bf16x8*)(&Ks[(16 * tm + fl) * 64 + gB]);
        }

        f32x4 st[4] = {};
        #pragma unroll
        for (int tm = 0; tm < 4; tm++) {
            st[tm] = __builtin_amdgcn_mfma_f32_16x16x32_bf16(kf[tm][0], qf[0], st[tm], 0, 0, 0);
            st[tm] = __builtin_amdgcn_mfma_f32_16x16x32_bf16(kf[tm][1], qf[1], st[tm], 0, 0, 0);
        }
        #pragma unroll
        for (int tm = 0; tm < 4; tm++) {
            float p0 = __builtin_amdgcn_exp2f(st[tm][0] * sc2);
            float p1 = __builtin_amdgcn_exp2f(st[tm][1] * sc2);
            float p2 = __builtin_amdgcn_exp2f(st[tm][2] * sc2);
            float p3 = __builtin_amdgcn_exp2f(st[tm][3] * sc2);
            lsum += (p0 + p1) + (p2 + p3);
            uint2 pk;
            pk.x = pack2(p0, p1);
            pk.y = pack2(p2, p3);
            *(uint2*)(&Ps[w][fl * 72 + 16 * tm + fq * 4]) = pk;
        }

        bf16x8 vf[4][2];
        #pragma unroll
        for (int jd = 0; jd < 4; jd++) {
            vf[jd][0] = *(const bf16x8*)(&Vs[(16 * jd + fl) * 64 + gA]);
            vf[jd][1] = *(const bf16x8*)(&Vs[(16 * jd + fl) * 64 + gB]);
        }
        bf16x8 pf0 = *(const bf16x8*)(&Ps[w][fl * 72 + fq * 8]);
        bf16x8 pf1 = *(const bf16x8*)(&Ps[w][fl * 72 + 32 + fq * 8]);
        #pragma unroll
        for (int jd = 0; jd < 4; jd++) {
            o[jd] = __builtin_amdgcn_mfma_f32_16x16x32_bf16(vf[jd][0], pf0, o[jd], 0, 0, 0);
            o[jd] = __builtin_amdgcn_mfma_f32_16x16x32_bf16(vf[jd][1], pf1, o[jd], 0, 0, 0);
        }
    }

    const int b = bh >> 3, h = bh & 7;
    float ls = lsum;
    ls += __shfl_xor(ls, 16);
    ls += __shfl_xor(ls, 32);
    const float linv = 1.f / ls;
    const size_t obase = ((size_t)(b * 1024 + wq + fl)) * 512 + h * 64;
    #pragma unroll
    for (int jd = 0; jd < 4; jd++) {
        const ushort4 qr = *(const ushort4*)(Qb + fl * 64 + 16 * jd + fq * 4);
        uint2 w2;
        w2.x = pack2(o[jd][0] * linv + bfu2f(qr.x), o[jd][1] * linv + bfu2f(qr.y));
        w2.y = pack2(o[jd][2] * linv + bfu2f(qr.z), o[jd][3] * linv + bfu2f(qr.w));
        *(uint2*)(&Oc[obase + 16 * jd + fq * 4]) = w2;
    }
}

// ---------------------------------------------------------------------------
// FUSED LayerNorm0 + O-projection + residual-relu + LayerNorm1 -> fp32 out.
// 256 blocks x 512 threads (8 waves). Block = 32 rows x ALL 512 cols.
// T14 async-split W loop (W(0) before A-stage; W(kt+1) after W(kt) pack).
// LDS: 32 + 64 + 2 = 98KB -> 1 block/CU.
// ---------------------------------------------------------------------------
__global__ __launch_bounds__(512) void gemm_fo_ln1(const bf16* __restrict__ A,
                                                   const float* __restrict__ Wo,
                                                   const float* __restrict__ g0,
                                                   const float* __restrict__ be0,
                                                   const float* __restrict__ bo,
                                                   const float* __restrict__ g1,
                                                   const float* __restrict__ be1,
                                                   float* __restrict__ out)
{
    __shared__ bf16 As[32 * 512];
    __shared__ bf16 Ws[512 * 64];
    __shared__ float2 red[32][8];

    const int tid = threadIdx.x, lane = tid & 63, w = tid >> 6;
    const int bm = blockIdx.x * 32;
    const int wn = w * 64;
    const int fr = lane & 15, fq = lane >> 4;

    // ---- Phase 1: stage A rows [bm, bm+32), granule-swizzled --------------
    const int ldb = 8 * tid;
    #pragma unroll
    for (int c = 0; c < 4; c++) {
        const int lin = tid + 512 * c;
        const int row = lin >> 6, g = lin & 63;
        gll16(A + (size_t)(bm + row) * 512 + ((g ^ (row & 7)) * 8),
              As + ldb + 4096 * c);
    }

    // T14: issue W chunk 0 now — latency hides under A-stage + ln0
    const int srow = tid >> 3;
    const int sg8  = (((tid & 7) ^ (srow & 7)) * 8);
    const float* Wp = Wo + (size_t)srow * 512 + sg8;
    float4 wr[8][2];
    #pragma unroll
    for (int c = 0; c < 8; c++) {
        const float* wp = Wp + (size_t)(64 * c) * 512;
        wr[c][0] = *(const float4*)(wp);
        wr[c][1] = *(const float4*)(wp + 4);
    }

    __syncthreads();   // A panel resident

    // ---- Phase 2: ln0 in place (row r: 16 threads x 32 cols each) ---------
    {
        const int r = tid >> 4, ci = tid & 15;
        const int lrow = r * 512;
        const int rx = (r & 7) * 8;
        float xv[4][8];
        float s = 0.f, s2 = 0.f;
        #pragma unroll
        for (int gg = 0; gg < 4; gg++) {
            const int g = ci * 4 + gg;
            const bf16x8 v = *(const bf16x8*)(&As[lrow + ((g * 8) ^ rx)]);
            #pragma unroll
            for (int e = 0; e < 8; e++) {
                const float f = bfu2f((unsigned short)v[e]);
                xv[gg][e] = f; s += f; s2 += f * f;
            }
        }
        #pragma unroll
        for (int off = 1; off < 16; off <<= 1) {
            s += __shfl_xor(s, off); s2 += __shfl_xor(s2, off);
        }
        const float mu  = s * (1.f / 512.f);
        const float var = s2 * (1.f / 512.f) - mu * mu;
        const float rs0 = rsqrtf(fmaxf(var, 0.f) + 1e-5f);
        #pragma unroll
        for (int gg = 0; gg < 4; gg++) {
            const int g = ci * 4 + gg;
            const float4 gv0 = *(const float4*)(g0 + g * 8);
            const float4 gv1 = *(const float4*)(g0 + g * 8 + 4);
            const float4 bv0 = *(const float4*)(be0 + g * 8);
            const float4 bv1 = *(const float4*)(be0 + g * 8 + 4);
            uint4 ov;
            ov.x = pack2((xv[gg][0]-mu)*rs0*gv0.x + bv0.x, (xv[gg][1]-mu)*rs0*gv0.y + bv0.y);
            ov.y = pack2((xv[gg][2]-mu)*rs0*gv0.z + bv0.z, (xv[gg][3]-mu)*rs0*gv0.w + bv0.w);
            ov.z = pack2((xv[gg][4]-mu)*rs0*gv1.x + bv1.x, (xv[gg][5]-mu)*rs0*gv1.y + bv1.y);
            ov.w = pack2((xv[gg][6]-mu)*rs0*gv1.z + bv1.z, (xv[gg][7]-mu)*rs0*gv1.w + bv1.w);
            *(uint4*)(&As[lrow + ((g * 8) ^ rx)]) = ov;
        }
    }
    __syncthreads();   // normalized panel visible to all

    // ---- Phase 3: GEMM over W chunks (fp32 Wo, T14-prefetched) ------------
    f32x4 acc[4][2] = {};

    for (int kt = 0; kt < 8; kt++) {
        if (kt) __syncthreads();
        // pack prefetched W chunk -> LDS
        #pragma unroll
        for (int c = 0; c < 8; c++) {
            uint4 wv;
            wv.x = pack2(wr[c][0].x, wr[c][0].y); wv.y = pack2(wr[c][0].z, wr[c][0].w);
            wv.z = pack2(wr[c][1].x, wr[c][1].y); wv.w = pack2(wr[c][1].z, wr[c][1].w);
            *(uint4*)(Ws + ldb + 4096 * c) = wv;
        }
        // issue next W chunk — in flight across barrier + MFMA
        if (kt < 7) {
            const int k1 = (kt + 1) * 64;
            #pragma unroll
            for (int c = 0; c < 8; c++) {
                const float* wp = Wp + k1 + (size_t)(64 * c) * 512;
                wr[c][0] = *(const float4*)(wp);
                wr[c][1] = *(const float4*)(wp + 4);
            }
        }
        __syncthreads();

        const int kb = kt * 8;
        #pragma unroll
        for (int c2 = 0; c2 < 2; c2++) {
            bf16x8 fx[2], fw[4];
            #pragma unroll
            for (int j = 0; j < 2; j++) {
                const int rx = 16 * j + fr;
                fx[j] = *(const bf16x8*)(&As[rx * 512 + (kb + ((c2 * 4 + fq) ^ (rx & 7))) * 8]);
            }
            #pragma unroll
            for (int i = 0; i < 4; i++) {
                const int rw = wn + 16 * i + fr;
                fw[i] = *(const bf16x8*)(&Ws[rw * 64 + (((c2 * 4 + fq) ^ (rw & 7)) * 8)]);
            }
            #pragma unroll
            for (int i = 0; i < 4; i++)
                #pragma unroll
                for (int j = 0; j < 2; j++)
                    acc[i][j] = __builtin_amdgcn_mfma_f32_16x16x32_bf16(fw[i], fx[j], acc[i][j], 0, 0, 0);
        }
    }

    // ---- Phase 4: y = R + relu(X + bo), block LN1, fp32 store -------------
    float yv[4][2][4];
    float s[2] = {0.f, 0.f}, s2[2] = {0.f, 0.f};
    #pragma unroll
    for (int i = 0; i < 4; i++) {
        const int c = wn + 16 * i + 4 * fq;
        const float4 bo4 = *(const float4*)(bo + c);
        const int gc = c >> 3, co = c & 7;
        #pragma unroll
        for (int j = 0; j < 2; j++) {
            const int n = 16 * j + fr;
            const ushort4 rr = *(const ushort4*)(&As[n * 512 + ((gc ^ (n & 7)) * 8 + co)]);
            float y0 = bfu2f(rr.x) + fmaxf(acc[i][j][0] + bo4.x, 0.f);
            float y1 = bfu2f(rr.y) + fmaxf(acc[i][j][1] + bo4.y, 0.f);
            float y2 = bfu2f(rr.z) + fmaxf(acc[i][j][2] + bo4.z, 0.f);
            float y3 = bfu2f(rr.w) + fmaxf(acc[i][j][3] + bo4.w, 0.f);
            s[j]  += (y0 + y1) + (y2 + y3);
            s2[j] += (y0 * y0 + y1 * y1) + (y2 * y2 + y3 * y3);
            yv[i][j][0] = y0; yv[i][j][1] = y1; yv[i][j][2] = y2; yv[i][j][3] = y3;
        }
    }
    #pragma unroll
    for (int j = 0; j < 2; j++) {
        s[j]  += __shfl_xor(s[j], 16);  s[j]  += __shfl_xor(s[j], 32);
        s2[j] += __shfl_xor(s2[j], 16); s2[j] += __shfl_xor(s2[j], 32);
    }
    if (fq == 0) {
        red[fr][w]      = make_float2(s[0], s2[0]);
        red[16 + fr][w] = make_float2(s[1], s2[1]);
    }
    __syncthreads();
    float mu[2], rs[2];
    #pragma unroll
    for (int j = 0; j < 2; j++) {
        const int n = 16 * j + fr;
        float S = 0.f, S2 = 0.f;
        #pragma unroll
        for (int q = 0; q < 8; q++) { const float2 v = red[n][q]; S += v.x; S2 += v.y; }
        mu[j] = S * (1.f / 512.f);
        const float var = S2 * (1.f / 512.f) - mu[j] * mu[j];
        rs[j] = rsqrtf(fmaxf(var, 0.f) + 1e-5f);
    }
    #pragma unroll
    for (int i = 0; i < 4; i++) {
        const int c = wn + 16 * i + 4 * fq;
        const float4 g4 = *(const float4*)(g1 + c);
        const float4 b4 = *(const float4*)(be1 + c);
        #pragma unroll
        for (int j = 0; j < 2; j++) {
            const int n = bm + 16 * j + fr;
            float4 o4;
            o4.x = (yv[i][j][0] - mu[j]) * rs[j] * g4.x + b4.x;
            o4.y = (yv[i][j][1] - mu[j]) * rs[j] * g4.y + b4.y;
            o4.z = (yv[i][j][2] - mu[j]) * rs[j] * g4.z + b4.z;
            o4.w = (yv[i][j][3] - mu[j]) * rs[j] * g4.w + b4.w;
            *(float4*)(out + (size_t)n * 512 + c) = o4;
        }
    }
}

// ---------------------------------------------------------------------------
extern "C" void kernel_launch(void* const* d_in, const int* in_sizes, int n_in,
                              void* d_out, int out_size, void* d_ws, size_t ws_size,
                              hipStream_t stream)
{
    const float* Q   = (const float*)d_in[0];
    const float* K   = (const float*)d_in[1];
    const float* Wq  = (const float*)d_in[2];
    const float* bq  = (const float*)d_in[3];
    const float* Wk  = (const float*)d_in[4];
    const float* bk  = (const float*)d_in[5];
    const float* Wv  = (const float*)d_in[6];
    const float* bv  = (const float*)d_in[7];
    const float* Wo  = (const float*)d_in[8];
    const float* bo  = (const float*)d_in[9];
    const float* g0  = (const float*)d_in[10];
    const float* be0 = (const float*)d_in[11];
    const float* g1  = (const float*)d_in[12];
    const float* be1 = (const float*)d_in[13];
    float* out = (float*)d_out;

    const size_t NQK = (size_t)8 * 1024 * 512;  // 4M elems
    bf16* ws   = (bf16*)d_ws;
    bf16* pQh  = ws;                 // [b,h,n,d]
    bf16* pKh  = pQh + NQK;          // [b,h,m,d]
    bf16* pVhT = pKh + NQK;          // [b,h,d,m]
    bf16* pOc  = pVhT + NQK;         // attn out [b,n,512] (workspace)

    gemm_qkv<<<dim3(64, 12), 256, 0, stream>>>(Q, K, Wq, Wk, Wv, bq, bk, bv, pQh, pKh, pVhT);
    attn_mfma<<<1024, 256, 0, stream>>>(pQh, pKh, pVhT, pOc);
    gemm_fo_ln1<<<256, 512, 0, stream>>>(pOc, Wo, g0, be0, bo, g1, be1, out);
}